// Round 6
// baseline (413.906 us; speedup 1.0000x reference)
//
#include <hip/hip_runtime.h>
#include <hip/hip_bf16.h>

#define N_GRAPHS 200
#define NPG      500
#define N_NODES_ 100000
#define N_EDGES_ 1600000
#define DIN      64
#define DG       128
#define SEQ      20
#define HL       128
#define G4       512
#define BWIN     (N_GRAPHS - SEQ + 1)  // 181
#define NPART    64
#define EPB      (N_EDGES_/NPART)      // 25000
#define NCNT     (N_GRAPHS*NPART)      // 12800
#define GPARTS   4                     // blocks per graph in k_gcn
#define TNPB     125                   // nodes per k_gcn block

__device__ __forceinline__ float sigmoidf_(float v){ return 1.0f/(1.0f+expf(-v)); }

// K1: per-(block,graph) edge counts via LDS histogram (no global atomics)
__global__ __launch_bounds__(256) void k_count(const int* __restrict__ src,
                                               int* __restrict__ cnt) {
  __shared__ int bins[N_GRAPHS];
  int b = blockIdx.x, t = threadIdx.x;
  for (int i = t; i < N_GRAPHS; i += 256) bins[i] = 0;
  __syncthreads();
  int e0 = b*EPB;
  for (int i = t; i < EPB; i += 256) atomicAdd(&bins[src[e0+i]/NPG], 1);
  __syncthreads();
  for (int g = t; g < N_GRAPHS; g += 256) cnt[g*NPART + b] = bins[g];
}

// K2: exclusive scan of 12800 counts in one block
__global__ __launch_bounds__(1024) void k_pscan(int* __restrict__ cnt) {
  __shared__ int sA[1024], sB[1024];
  int t = threadIdx.x;
  int base = t*13;
  int loc[13]; int s = 0;
  #pragma unroll
  for (int j = 0; j < 13; ++j) {
    int idx = base + j;
    int v = (idx < NCNT) ? cnt[idx] : 0;
    loc[j] = s; s += v;
  }
  sA[t] = s; __syncthreads();
  int* cur = sA; int* nxt = sB;
  for (int off = 1; off < 1024; off <<= 1) {
    nxt[t] = cur[t] + ((t >= off) ? cur[t-off] : 0);
    __syncthreads();
    int* tmp = cur; cur = nxt; nxt = tmp;
  }
  int excl = cur[t] - s;
  #pragma unroll
  for (int j = 0; j < 13; ++j) {
    int idx = base + j;
    if (idx < NCNT) cnt[idx] = excl + loc[j];
  }
}

// K3: deterministic partition by graph; packed (src_local<<9 | dst_local)
__global__ __launch_bounds__(256) void k_part(const int* __restrict__ src,
                                              const int* __restrict__ dst,
                                              const int* __restrict__ cnt,
                                              int* __restrict__ part) {
  __shared__ int cur[N_GRAPHS];
  int b = blockIdx.x, t = threadIdx.x;
  for (int g = t; g < N_GRAPHS; g += 256) cur[g] = cnt[g*NPART + b];
  __syncthreads();
  int e0 = b*EPB;
  for (int i = t; i < EPB; i += 256) {
    int s = src[e0+i], d = dst[e0+i];
    int g = s / NPG;
    int sl = s - g*NPG, dl = d - g*NPG;
    int pos = atomicAdd(&cur[g], 1);
    part[pos] = (sl << 9) | dl;
  }
}

// K4: per-graph counting sort -> global sorted src list + node metadata
__global__ __launch_bounds__(512) void k_sort(const int* __restrict__ cnt,
    const int* __restrict__ part, unsigned short* __restrict__ sorted_all,
    float* __restrict__ so_all, int* __restrict__ e_end, int* __restrict__ e_deg) {
  __shared__ int indeg[NPG], outdeg[NPG], off[NPG];
  __shared__ int sA[512], sB[512];
  int g = blockIdx.x, t = threadIdx.x;
  int seg0 = cnt[g*NPART];
  int seg1 = (g == N_GRAPHS-1) ? N_EDGES_ : cnt[(g+1)*NPART];
  if (t < NPG) { indeg[t] = 0; outdeg[t] = 0; }
  __syncthreads();
  for (int e = seg0 + t; e < seg1; e += 512) {
    int p = part[e];
    atomicAdd(&indeg[p & 511], 1);
    atomicAdd(&outdeg[p >> 9], 1);
  }
  __syncthreads();
  int v = (t < NPG) ? indeg[t] : 0;
  sA[t] = v; __syncthreads();
  int* cur = sA; int* nxt = sB;
  for (int o = 1; o < 512; o <<= 1) {
    nxt[t] = cur[t] + ((t >= o) ? cur[t-o] : 0);
    __syncthreads();
    int* tmp = cur; cur = nxt; nxt = tmp;
  }
  if (t < NPG) off[t] = cur[t] - v;
  __syncthreads();
  for (int e = seg0 + t; e < seg1; e += 512) {
    int p = part[e];
    int pos = atomicAdd(&off[p & 511], 1);
    sorted_all[seg0 + pos] = (unsigned short)(p >> 9);
  }
  __syncthreads();
  if (t < NPG) {
    so_all[g*NPG + t] = rsqrtf((float)max(outdeg[t], 1));
    e_end[g*NPG + t]  = seg0 + off[t];
    e_deg[g*NPG + t]  = indeg[t];
  }
}

// K5: aggregation — one wave per node, quarter-wave x 4-unroll per edge
__global__ __launch_bounds__(256) void k_agg(const float* __restrict__ x,
    const float* __restrict__ so_all, const int* __restrict__ e_end,
    const int* __restrict__ e_deg, const unsigned short* __restrict__ sorted_all,
    float* __restrict__ hpre) {
  int t = threadIdx.x;
  int n = (blockIdx.x << 2) + (t >> 6);
  if (n >= N_NODES_) return;
  int lane = t & 63, q = lane >> 4, ql = lane & 15;
  int end = e_end[n], deg = e_deg[n], start = end - deg;
  int g = n / NPG;
  const float4* xg = ((const float4*)x) + (size_t)g*NPG*16;
  const float* sog = so_all + g*NPG;
  float4 acc = make_float4(0.f, 0.f, 0.f, 0.f);
  for (int i = start + (q << 2); i < end; i += 16) {
    int sj[4];
    #pragma unroll
    for (int j = 0; j < 4; ++j) sj[j] = (i + j < end) ? (int)sorted_all[i+j] : -1;
    #pragma unroll
    for (int j = 0; j < 4; ++j) if (sj[j] >= 0) {
      float sc = sog[sj[j]];
      float4 xv = xg[(size_t)sj[j]*16 + ql];
      acc.x += xv.x*sc; acc.y += xv.y*sc; acc.z += xv.z*sc; acc.w += xv.w*sc;
    }
  }
  acc.x += __shfl_xor(acc.x, 16); acc.y += __shfl_xor(acc.y, 16);
  acc.z += __shfl_xor(acc.z, 16); acc.w += __shfl_xor(acc.w, 16);
  acc.x += __shfl_xor(acc.x, 32); acc.y += __shfl_xor(acc.y, 32);
  acc.z += __shfl_xor(acc.z, 32); acc.w += __shfl_xor(acc.w, 32);
  if (q == 0) {
    float sn = rsqrtf((float)max(deg, 1));
    float4 r = make_float4(acc.x*sn, acc.y*sn, acc.z*sn, acc.w*sn);
    ((float4*)hpre)[(size_t)n*16 + ql] = r;
  }
}

// K6: GCN GEMM + ReLU + partial pool.
// Thread = one output dim, w-column (64 floats) in VGPRs; h loads are
// wave-uniform broadcasts. __launch_bounds__(256,4) -> 128-VGPR budget so the
// compiler KEEPS wreg resident (round-4 failure mode: default bounds -> 64-VGPR
// target -> w re-loaded per node; round-5 failure mode: 256 VGPR + 68KB LDS ->
// 8.7% occupancy).
__global__ __launch_bounds__(256, 4) void k_gcn(const float* __restrict__ hpre,
    const float* __restrict__ w_gcn, const float* __restrict__ b_gcn,
    float* __restrict__ hgpart) {
  __shared__ float pS[2*DG];
  int t = threadIdx.x, bb = blockIdx.x;
  int d = t & 127, parity = t >> 7;      // parity is wave-uniform
  int g = bb >> 2, p = bb & 3;
  int nbase = g*NPG + p*TNPB;
  float4 w4[16];
  #pragma unroll
  for (int k4 = 0; k4 < 16; ++k4) {
    float4 v;
    v.x = w_gcn[(4*k4+0)*DG + d];
    v.y = w_gcn[(4*k4+1)*DG + d];
    v.z = w_gcn[(4*k4+2)*DG + d];
    v.w = w_gcn[(4*k4+3)*DG + d];
    w4[k4] = v;
  }
  float bgd = b_gcn[d];
  float psum = 0.0f;
  for (int n = parity; n < TNPB; n += 2) {
    const float4* hp = (const float4*)(hpre + (size_t)(nbase+n)*DIN);
    float acc = bgd;
    #pragma unroll
    for (int k4 = 0; k4 < 16; ++k4) {
      float4 h4 = hp[k4];
      acc = fmaf(h4.x, w4[k4].x, acc);
      acc = fmaf(h4.y, w4[k4].y, acc);
      acc = fmaf(h4.z, w4[k4].z, acc);
      acc = fmaf(h4.w, w4[k4].w, acc);
    }
    psum += fmaxf(acc, 0.0f);
  }
  pS[parity*DG + d] = psum;
  __syncthreads();
  if (t < DG) hgpart[(size_t)bb*DG + t] = pS[t] + pS[DG + t];
}

// K7: combine partials, divide by node count
__global__ void k_pool(const float* __restrict__ hgpart, float* __restrict__ hg) {
  int idx = blockIdx.x*blockDim.x + threadIdx.x;
  if (idx >= N_GRAPHS*DG) return;
  int g = idx >> 7, d = idx & 127;
  float s = 0.0f;
  #pragma unroll
  for (int p = 0; p < GPARTS; ++p) s += hgpart[(size_t)(g*GPARTS+p)*DG + d];
  hg[idx] = s * (1.0f/NPG);
}

// K8: per-graph input projection
__global__ __launch_bounds__(512) void k_proj(const float* __restrict__ hg,
    const float* __restrict__ w_ih, const float* __restrict__ b_ih,
    float* __restrict__ proj) {
  __shared__ __align__(16) float hS[HL];
  int g = blockIdx.x, r = threadIdx.x;
  if (r < HL) hS[r] = hg[g*HL + r];
  __syncthreads();
  const float4* wr = (const float4*)(w_ih + (size_t)r*HL);
  const float4* hv = (const float4*)hS;
  float acc = b_ih[r];
  #pragma unroll
  for (int k4 = 0; k4 < 32; ++k4) {
    float4 w4 = wr[k4]; float4 h4 = hv[k4];
    acc += w4.x*h4.x + w4.y*h4.y + w4.z*h4.z + w4.w*h4.w;
  }
  proj[(size_t)g*G4 + r] = acc;
}

// K9: LSTM, block per window, thread per gate-row, w_hh row in VGPRs
__global__ __launch_bounds__(512) void k_lstm(const float* __restrict__ proj,
    const float* __restrict__ w_hh, const float* __restrict__ b_hh,
    const float* __restrict__ w_fc, const float* __restrict__ b_fc,
    float* __restrict__ out) {
  __shared__ __align__(16) float hS[HL];
  __shared__ float gS[G4];
  int b = blockIdx.x, r = threadIdx.x;
  float wreg[HL];
  const float4* wr = (const float4*)(w_hh + (size_t)r*HL);
  #pragma unroll
  for (int k4 = 0; k4 < 32; ++k4) {
    float4 w4 = wr[k4];
    wreg[k4*4+0]=w4.x; wreg[k4*4+1]=w4.y; wreg[k4*4+2]=w4.z; wreg[k4*4+3]=w4.w;
  }
  float bh = b_hh[r];
  float c = 0.0f;
  if (r < HL) hS[r] = 0.0f;
  __syncthreads();
  for (int l = 0; l < SEQ; ++l) {
    float acc = proj[(size_t)(b+l)*G4 + r] + bh;
    const float4* hv = (const float4*)hS;
    #pragma unroll
    for (int k4 = 0; k4 < 32; ++k4) {
      float4 h4 = hv[k4];
      acc += h4.x*wreg[k4*4] + h4.y*wreg[k4*4+1] + h4.z*wreg[k4*4+2] + h4.w*wreg[k4*4+3];
    }
    gS[r] = acc;
    __syncthreads();
    if (r < HL) {
      float gi = sigmoidf_(gS[r]);
      float gf = sigmoidf_(gS[HL + r]);
      float gg = tanhf(gS[2*HL + r]);
      float go = sigmoidf_(gS[3*HL + r]);
      c = gf*c + gi*gg;
      hS[r] = go * tanhf(c);
    }
    __syncthreads();
  }
  if (r < 64) {
    float s = hS[r]*w_fc[r] + hS[r+64]*w_fc[r+64];
    #pragma unroll
    for (int off = 32; off > 0; off >>= 1) s += __shfl_down(s, off);
    if (r == 0) out[b] = s + b_fc[0];
  }
}

extern "C" void kernel_launch(void* const* d_in, const int* in_sizes, int n_in,
                              void* d_out, int out_size, void* d_ws, size_t ws_size,
                              hipStream_t stream) {
  const float* x     = (const float*)d_in[0];
  const int*   src   = (const int*)d_in[1];
  const int*   dst   = (const int*)d_in[2];
  const float* w_gcn = (const float*)d_in[4];
  const float* b_gcn = (const float*)d_in[5];
  const float* w_ih  = (const float*)d_in[6];
  const float* w_hh  = (const float*)d_in[7];
  const float* b_ih  = (const float*)d_in[8];
  const float* b_hh  = (const float*)d_in[9];
  const float* w_fc  = (const float*)d_in[10];
  const float* b_fc  = (const float*)d_in[11];
  float* out = (float*)d_out;

  char* ws = (char*)d_ws;
  size_t off = 0;
  auto alloc = [&](size_t bytes) -> void* {
    void* p = ws + off; off += (bytes + 255) & ~(size_t)255; return p;
  };
  int* cnt     = (int*)alloc((size_t)NCNT*4);
  int* part    = (int*)alloc((size_t)N_EDGES_*4);
  unsigned short* sorted_all = (unsigned short*)alloc((size_t)N_EDGES_*2);
  float* so_all = (float*)alloc((size_t)N_NODES_*4);
  int* e_end   = (int*)alloc((size_t)N_NODES_*4);
  int* e_deg   = (int*)alloc((size_t)N_NODES_*4);
  float* hpre  = (float*)alloc((size_t)N_NODES_*DIN*4);
  float* hgpart= (float*)alloc((size_t)N_GRAPHS*GPARTS*DG*4);
  float* hg    = (float*)alloc((size_t)N_GRAPHS*DG*4);
  float* proj  = (float*)alloc((size_t)N_GRAPHS*G4*4);
  (void)ws_size; (void)in_sizes; (void)n_in; (void)out_size;

  k_count<<<NPART, 256, 0, stream>>>(src, cnt);
  k_pscan<<<1, 1024, 0, stream>>>(cnt);
  k_part<<<NPART, 256, 0, stream>>>(src, dst, cnt, part);
  k_sort<<<N_GRAPHS, 512, 0, stream>>>(cnt, part, sorted_all, so_all, e_end, e_deg);
  k_agg<<<(N_NODES_+3)/4, 256, 0, stream>>>(x, so_all, e_end, e_deg, sorted_all, hpre);
  k_gcn<<<N_GRAPHS*GPARTS, 256, 0, stream>>>(hpre, w_gcn, b_gcn, hgpart);
  k_pool<<<(N_GRAPHS*DG+255)/256, 256, 0, stream>>>(hgpart, hg);
  k_proj<<<N_GRAPHS, 512, 0, stream>>>(hg, w_ih, b_ih, proj);
  k_lstm<<<BWIN, 512, 0, stream>>>(proj, w_hh, b_hh, w_fc, b_fc, out);
}

// Round 7
// 290.821 us; speedup vs baseline: 1.4232x; 1.4232x over previous
//
#include <hip/hip_runtime.h>
#include <hip/hip_bf16.h>

#define N_GRAPHS 200
#define NPG      500
#define NPGP     512                   // padded nodes per graph (MFMA tiles)
#define N_NODES_ 100000
#define N_EDGES_ 1600000
#define DIN      64
#define DG       128
#define SEQ      20
#define HL       128
#define G4       512
#define BWIN     (N_GRAPHS - SEQ + 1)  // 181
#define NPART    64
#define EPB      (N_EDGES_/NPART)      // 25000
#define NCNT     (N_GRAPHS*NPART)      // 12800

typedef __attribute__((ext_vector_type(8))) short short8;
typedef __attribute__((ext_vector_type(4))) float float4v;

__device__ __forceinline__ float sigmoidf_(float v){ return 1.0f/(1.0f+expf(-v)); }

// fp32 -> bf16 round-to-nearest-even
__device__ __forceinline__ unsigned short f2bf(float f) {
  unsigned int u = __float_as_uint(f);
  u += 0x7fffu + ((u >> 16) & 1u);
  return (unsigned short)(u >> 16);
}

// K1: per-(block,graph) edge counts via LDS histogram (no global atomics)
__global__ __launch_bounds__(256) void k_count(const int* __restrict__ src,
                                               int* __restrict__ cnt) {
  __shared__ int bins[N_GRAPHS];
  int b = blockIdx.x, t = threadIdx.x;
  for (int i = t; i < N_GRAPHS; i += 256) bins[i] = 0;
  __syncthreads();
  int e0 = b*EPB;
  for (int i = t; i < EPB; i += 256) atomicAdd(&bins[src[e0+i]/NPG], 1);
  __syncthreads();
  for (int g = t; g < N_GRAPHS; g += 256) cnt[g*NPART + b] = bins[g];
}

// K2: exclusive scan of 12800 counts in one block
__global__ __launch_bounds__(1024) void k_pscan(int* __restrict__ cnt) {
  __shared__ int sA[1024], sB[1024];
  int t = threadIdx.x;
  int base = t*13;
  int loc[13]; int s = 0;
  #pragma unroll
  for (int j = 0; j < 13; ++j) {
    int idx = base + j;
    int v = (idx < NCNT) ? cnt[idx] : 0;
    loc[j] = s; s += v;
  }
  sA[t] = s; __syncthreads();
  int* cur = sA; int* nxt = sB;
  for (int off = 1; off < 1024; off <<= 1) {
    nxt[t] = cur[t] + ((t >= off) ? cur[t-off] : 0);
    __syncthreads();
    int* tmp = cur; cur = nxt; nxt = tmp;
  }
  int excl = cur[t] - s;
  #pragma unroll
  for (int j = 0; j < 13; ++j) {
    int idx = base + j;
    if (idx < NCNT) cnt[idx] = excl + loc[j];
  }
}

// K3: deterministic partition by graph; packed (src_local<<9 | dst_local)
__global__ __launch_bounds__(256) void k_part(const int* __restrict__ src,
                                              const int* __restrict__ dst,
                                              const int* __restrict__ cnt,
                                              int* __restrict__ part) {
  __shared__ int cur[N_GRAPHS];
  int b = blockIdx.x, t = threadIdx.x;
  for (int g = t; g < N_GRAPHS; g += 256) cur[g] = cnt[g*NPART + b];
  __syncthreads();
  int e0 = b*EPB;
  for (int i = t; i < EPB; i += 256) {
    int s = src[e0+i], d = dst[e0+i];
    int g = s / NPG;
    int sl = s - g*NPG, dl = d - g*NPG;
    int pos = atomicAdd(&cur[g], 1);
    part[pos] = (sl << 9) | dl;
  }
}

// K4: per-graph counting sort -> global sorted src list + node metadata
__global__ __launch_bounds__(512) void k_sort(const int* __restrict__ cnt,
    const int* __restrict__ part, unsigned short* __restrict__ sorted_all,
    float* __restrict__ so_all, int* __restrict__ e_end, int* __restrict__ e_deg) {
  __shared__ int indeg[NPG], outdeg[NPG], off[NPG];
  __shared__ int sA[512], sB[512];
  int g = blockIdx.x, t = threadIdx.x;
  int seg0 = cnt[g*NPART];
  int seg1 = (g == N_GRAPHS-1) ? N_EDGES_ : cnt[(g+1)*NPART];
  if (t < NPG) { indeg[t] = 0; outdeg[t] = 0; }
  __syncthreads();
  for (int e = seg0 + t; e < seg1; e += 512) {
    int p = part[e];
    atomicAdd(&indeg[p & 511], 1);
    atomicAdd(&outdeg[p >> 9], 1);
  }
  __syncthreads();
  int v = (t < NPG) ? indeg[t] : 0;
  sA[t] = v; __syncthreads();
  int* cur = sA; int* nxt = sB;
  for (int o = 1; o < 512; o <<= 1) {
    nxt[t] = cur[t] + ((t >= o) ? cur[t-o] : 0);
    __syncthreads();
    int* tmp = cur; cur = nxt; nxt = tmp;
  }
  if (t < NPG) off[t] = cur[t] - v;
  __syncthreads();
  for (int e = seg0 + t; e < seg1; e += 512) {
    int p = part[e];
    int pos = atomicAdd(&off[p & 511], 1);
    sorted_all[seg0 + pos] = (unsigned short)(p >> 9);
  }
  __syncthreads();
  if (t < NPG) {
    so_all[g*NPG + t] = rsqrtf((float)max(outdeg[t], 1));
    e_end[g*NPG + t]  = seg0 + off[t];
    e_deg[g*NPG + t]  = indeg[t];
  }
}

// K5: aggregation — one wave per PADDED node slot; writes bf16 hpreb [g][512][64]
__global__ __launch_bounds__(256) void k_agg(const float* __restrict__ x,
    const float* __restrict__ so_all, const int* __restrict__ e_end,
    const int* __restrict__ e_deg, const unsigned short* __restrict__ sorted_all,
    unsigned short* __restrict__ hpreb) {
  int t = threadIdx.x;
  int npad = (blockIdx.x << 2) + (t >> 6);
  if (npad >= N_GRAPHS*NPGP) return;
  int g = npad >> 9, nl = npad & 511;
  int lane = t & 63, q = lane >> 4, ql = lane & 15;
  if (nl >= NPG) {                      // pad row -> zeros
    if (q == 0) {
      ushort4 z; z.x = z.y = z.z = z.w = 0;
      *(ushort4*)(hpreb + (size_t)npad*DIN + ql*4) = z;
    }
    return;
  }
  int n = g*NPG + nl;
  int end = e_end[n], deg = e_deg[n], start = end - deg;
  const float4* xg = ((const float4*)x) + (size_t)g*NPG*16;
  const float* sog = so_all + g*NPG;
  float4 acc = make_float4(0.f, 0.f, 0.f, 0.f);
  for (int i = start + (q << 2); i < end; i += 16) {
    int sj[4];
    #pragma unroll
    for (int j = 0; j < 4; ++j) sj[j] = (i + j < end) ? (int)sorted_all[i+j] : -1;
    #pragma unroll
    for (int j = 0; j < 4; ++j) if (sj[j] >= 0) {
      float sc = sog[sj[j]];
      float4 xv = xg[(size_t)sj[j]*16 + ql];
      acc.x += xv.x*sc; acc.y += xv.y*sc; acc.z += xv.z*sc; acc.w += xv.w*sc;
    }
  }
  acc.x += __shfl_xor(acc.x, 16); acc.y += __shfl_xor(acc.y, 16);
  acc.z += __shfl_xor(acc.z, 16); acc.w += __shfl_xor(acc.w, 16);
  acc.x += __shfl_xor(acc.x, 32); acc.y += __shfl_xor(acc.y, 32);
  acc.z += __shfl_xor(acc.z, 32); acc.w += __shfl_xor(acc.w, 32);
  if (q == 0) {
    float sn = rsqrtf((float)max(deg, 1));
    ushort4 uv;
    uv.x = f2bf(acc.x*sn); uv.y = f2bf(acc.y*sn);
    uv.z = f2bf(acc.z*sn); uv.w = f2bf(acc.w*sn);
    *(ushort4*)(hpreb + (size_t)npad*DIN + ql*4) = uv;
  }
}

// K6a: swizzle w_gcn (fp32 [64][128]) into bf16 B-fragment layout.
// frag f = nt*2 + h (nt: 16-col tile, h: K-half). Element j of lane l:
// w[k = h*32 + (l>>4)*8 + j][n = nt*16 + (l&15)]
__global__ __launch_bounds__(256) void k_wprep(const float* __restrict__ w_gcn,
                                               unsigned short* __restrict__ wB) {
  int t = threadIdx.x;
  int lane = t & 63;
  for (int f = t >> 6; f < 16; f += 4) {
    int h = f & 1, nt = f >> 1;
    int kbase = h*32 + (lane >> 4)*8;
    int n = nt*16 + (lane & 15);
    #pragma unroll
    for (int j = 0; j < 8; ++j)
      wB[(f*64 + lane)*8 + j] = f2bf(w_gcn[(kbase + j)*DG + n]);
  }
}

// K6b: MFMA GCN GEMM + ReLU + mean pool. Block = one graph (512 padded rows).
// 4 waves x 8 rowtiles x 8 ntiles x 2 K-halves = 512 mfma_f32_16x16x32_bf16.
// D layout: col = lane&15, row = (lane>>4)*4 + reg. Pad rows masked pre-pool.
__global__ __launch_bounds__(256) void k_gcn(
    const unsigned short* __restrict__ hpreb,
    const unsigned short* __restrict__ wB,
    const float* __restrict__ b_gcn,
    float* __restrict__ hg) {
  __shared__ unsigned short wLds[16*64*8];   // 16 KB
  __shared__ float pS[4*DG];
  int t = threadIdx.x, g = blockIdx.x;
  for (int i = t; i < 16*64; i += 256)
    ((short8*)wLds)[i] = ((const short8*)wB)[i];
  __syncthreads();
  int w = t >> 6, lane = t & 63;
  int quad = lane >> 4, l15 = lane & 15;
  float bcol[8];
  #pragma unroll
  for (int nt = 0; nt < 8; ++nt) bcol[nt] = b_gcn[nt*16 + l15];
  float psum[8] = {0.f,0.f,0.f,0.f,0.f,0.f,0.f,0.f};
  const unsigned short* hb = hpreb + (size_t)g*NPGP*DIN;
  for (int i = 0; i < 8; ++i) {
    int rt = w + 4*i;
    int row0 = rt*16;
    const short8* aptr = (const short8*)(hb + (size_t)(row0 + l15)*DIN + quad*8);
    short8 a0 = aptr[0];   // k = quad*8 + [0..8)      (K-half 0)
    short8 a1 = aptr[4];   // k = 32 + quad*8 + [0..8) (K-half 1)
    #pragma unroll
    for (int nt = 0; nt < 8; ++nt) {
      short8 b0 = *((const short8*)&wLds[((nt*2+0)*64 + lane)*8]);
      short8 b1 = *((const short8*)&wLds[((nt*2+1)*64 + lane)*8]);
      float4v acc = {0.f, 0.f, 0.f, 0.f};
      acc = __builtin_amdgcn_mfma_f32_16x16x32_bf16(a0, b0, acc, 0, 0, 0);
      acc = __builtin_amdgcn_mfma_f32_16x16x32_bf16(a1, b1, acc, 0, 0, 0);
      #pragma unroll
      for (int r = 0; r < 4; ++r) {
        int node = row0 + quad*4 + r;
        float v = acc[r] + bcol[nt];
        psum[nt] += (node < NPG) ? fmaxf(v, 0.f) : 0.f;
      }
    }
  }
  #pragma unroll
  for (int nt = 0; nt < 8; ++nt) {
    float v = psum[nt];
    v += __shfl_xor(v, 16);
    v += __shfl_xor(v, 32);
    if (lane < 16) pS[w*DG + nt*16 + lane] = v;
  }
  __syncthreads();
  if (t < DG)
    hg[g*DG + t] = (pS[t] + pS[DG+t] + pS[2*DG+t] + pS[3*DG+t]) * (1.0f/NPG);
}

// K7: per-graph input projection
__global__ __launch_bounds__(512) void k_proj(const float* __restrict__ hg,
    const float* __restrict__ w_ih, const float* __restrict__ b_ih,
    float* __restrict__ proj) {
  __shared__ __align__(16) float hS[HL];
  int g = blockIdx.x, r = threadIdx.x;
  if (r < HL) hS[r] = hg[g*HL + r];
  __syncthreads();
  const float4* wr = (const float4*)(w_ih + (size_t)r*HL);
  const float4* hv = (const float4*)hS;
  float acc = b_ih[r];
  #pragma unroll
  for (int k4 = 0; k4 < 32; ++k4) {
    float4 w4 = wr[k4]; float4 h4 = hv[k4];
    acc += w4.x*h4.x + w4.y*h4.y + w4.z*h4.z + w4.w*h4.w;
  }
  proj[(size_t)g*G4 + r] = acc;
}

// K8: LSTM, block per window, thread per gate-row
__global__ __launch_bounds__(512) void k_lstm(const float* __restrict__ proj,
    const float* __restrict__ w_hh, const float* __restrict__ b_hh,
    const float* __restrict__ w_fc, const float* __restrict__ b_fc,
    float* __restrict__ out) {
  __shared__ __align__(16) float hS[HL];
  __shared__ float gS[G4];
  int b = blockIdx.x, r = threadIdx.x;
  float wreg[HL];
  const float4* wr = (const float4*)(w_hh + (size_t)r*HL);
  #pragma unroll
  for (int k4 = 0; k4 < 32; ++k4) {
    float4 w4 = wr[k4];
    wreg[k4*4+0]=w4.x; wreg[k4*4+1]=w4.y; wreg[k4*4+2]=w4.z; wreg[k4*4+3]=w4.w;
  }
  float bh = b_hh[r];
  float c = 0.0f;
  if (r < HL) hS[r] = 0.0f;
  __syncthreads();
  for (int l = 0; l < SEQ; ++l) {
    float acc = proj[(size_t)(b+l)*G4 + r] + bh;
    const float4* hv = (const float4*)hS;
    #pragma unroll
    for (int k4 = 0; k4 < 32; ++k4) {
      float4 h4 = hv[k4];
      acc += h4.x*wreg[k4*4] + h4.y*wreg[k4*4+1] + h4.z*wreg[k4*4+2] + h4.w*wreg[k4*4+3];
    }
    gS[r] = acc;
    __syncthreads();
    if (r < HL) {
      float gi = sigmoidf_(gS[r]);
      float gf = sigmoidf_(gS[HL + r]);
      float gg = tanhf(gS[2*HL + r]);
      float go = sigmoidf_(gS[3*HL + r]);
      c = gf*c + gi*gg;
      hS[r] = go * tanhf(c);
    }
    __syncthreads();
  }
  if (r < 64) {
    float s = hS[r]*w_fc[r] + hS[r+64]*w_fc[r+64];
    #pragma unroll
    for (int off = 32; off > 0; off >>= 1) s += __shfl_down(s, off);
    if (r == 0) out[b] = s + b_fc[0];
  }
}

extern "C" void kernel_launch(void* const* d_in, const int* in_sizes, int n_in,
                              void* d_out, int out_size, void* d_ws, size_t ws_size,
                              hipStream_t stream) {
  const float* x     = (const float*)d_in[0];
  const int*   src   = (const int*)d_in[1];
  const int*   dst   = (const int*)d_in[2];
  const float* w_gcn = (const float*)d_in[4];
  const float* b_gcn = (const float*)d_in[5];
  const float* w_ih  = (const float*)d_in[6];
  const float* w_hh  = (const float*)d_in[7];
  const float* b_ih  = (const float*)d_in[8];
  const float* b_hh  = (const float*)d_in[9];
  const float* w_fc  = (const float*)d_in[10];
  const float* b_fc  = (const float*)d_in[11];
  float* out = (float*)d_out;

  char* ws = (char*)d_ws;
  size_t off = 0;
  auto alloc = [&](size_t bytes) -> void* {
    void* p = ws + off; off += (bytes + 255) & ~(size_t)255; return p;
  };
  int* cnt     = (int*)alloc((size_t)NCNT*4);
  int* part    = (int*)alloc((size_t)N_EDGES_*4);
  unsigned short* sorted_all = (unsigned short*)alloc((size_t)N_EDGES_*2);
  float* so_all = (float*)alloc((size_t)N_NODES_*4);
  int* e_end   = (int*)alloc((size_t)N_NODES_*4);
  int* e_deg   = (int*)alloc((size_t)N_NODES_*4);
  unsigned short* hpreb = (unsigned short*)alloc((size_t)N_GRAPHS*NPGP*DIN*2);
  unsigned short* wB    = (unsigned short*)alloc((size_t)16*64*8*2);
  float* hg    = (float*)alloc((size_t)N_GRAPHS*DG*4);
  float* proj  = (float*)alloc((size_t)N_GRAPHS*G4*4);
  (void)ws_size; (void)in_sizes; (void)n_in; (void)out_size;

  k_count<<<NPART, 256, 0, stream>>>(src, cnt);
  k_pscan<<<1, 1024, 0, stream>>>(cnt);
  k_part<<<NPART, 256, 0, stream>>>(src, dst, cnt, part);
  k_sort<<<N_GRAPHS, 512, 0, stream>>>(cnt, part, sorted_all, so_all, e_end, e_deg);
  k_wprep<<<1, 256, 0, stream>>>(w_gcn, wB);
  k_agg<<<(N_GRAPHS*NPGP)/4, 256, 0, stream>>>(x, so_all, e_end, e_deg, sorted_all, hpreb);
  k_gcn<<<N_GRAPHS, 256, 0, stream>>>(hpreb, wB, b_gcn, hg);
  k_proj<<<N_GRAPHS, 512, 0, stream>>>(hg, w_ih, b_ih, proj);
  k_lstm<<<BWIN, 512, 0, stream>>>(proj, w_hh, b_hh, w_fc, b_fc, out);
}

// Round 8
// 275.720 us; speedup vs baseline: 1.5012x; 1.0548x over previous
//
#include <hip/hip_runtime.h>
#include <hip/hip_bf16.h>

#define N_GRAPHS 200
#define NPG      500
#define NPGP     512                   // padded nodes per graph (MFMA tiles)
#define N_NODES_ 100000
#define N_EDGES_ 1600000
#define DIN      64
#define DG       128
#define SEQ      20
#define HL       128
#define G4       512
#define BWIN     (N_GRAPHS - SEQ + 1)  // 181
#define NPART    64
#define EPB      (N_EDGES_/NPART)      // 25000
#define NCNT     (N_GRAPHS*NPART)      // 12800

typedef __attribute__((ext_vector_type(8))) short short8;
typedef __attribute__((ext_vector_type(4))) float float4v;

__device__ __forceinline__ float sigmoidf_(float v){ return 1.0f/(1.0f+expf(-v)); }

// fp32 -> bf16 round-to-nearest-even
__device__ __forceinline__ unsigned short f2bf(float f) {
  unsigned int u = __float_as_uint(f);
  u += 0x7fffu + ((u >> 16) & 1u);
  return (unsigned short)(u >> 16);
}

// K1: per-(block,graph) edge counts via LDS histogram (no global atomics)
__global__ __launch_bounds__(256) void k_count(const int* __restrict__ src,
                                               int* __restrict__ cnt) {
  __shared__ int bins[N_GRAPHS];
  int b = blockIdx.x, t = threadIdx.x;
  for (int i = t; i < N_GRAPHS; i += 256) bins[i] = 0;
  __syncthreads();
  int e0 = b*EPB;
  for (int i = t; i < EPB; i += 256) atomicAdd(&bins[src[e0+i]/NPG], 1);
  __syncthreads();
  for (int g = t; g < N_GRAPHS; g += 256) cnt[g*NPART + b] = bins[g];
}

// K2: exclusive scan of 12800 counts in one block
__global__ __launch_bounds__(1024) void k_pscan(int* __restrict__ cnt) {
  __shared__ int sA[1024], sB[1024];
  int t = threadIdx.x;
  int base = t*13;
  int loc[13]; int s = 0;
  #pragma unroll
  for (int j = 0; j < 13; ++j) {
    int idx = base + j;
    int v = (idx < NCNT) ? cnt[idx] : 0;
    loc[j] = s; s += v;
  }
  sA[t] = s; __syncthreads();
  int* cur = sA; int* nxt = sB;
  for (int off = 1; off < 1024; off <<= 1) {
    nxt[t] = cur[t] + ((t >= off) ? cur[t-off] : 0);
    __syncthreads();
    int* tmp = cur; cur = nxt; nxt = tmp;
  }
  int excl = cur[t] - s;
  #pragma unroll
  for (int j = 0; j < 13; ++j) {
    int idx = base + j;
    if (idx < NCNT) cnt[idx] = excl + loc[j];
  }
}

// K3: deterministic partition by graph; packed (src_local<<9 | dst_local)
__global__ __launch_bounds__(256) void k_part(const int* __restrict__ src,
                                              const int* __restrict__ dst,
                                              const int* __restrict__ cnt,
                                              int* __restrict__ part) {
  __shared__ int cur[N_GRAPHS];
  int b = blockIdx.x, t = threadIdx.x;
  for (int g = t; g < N_GRAPHS; g += 256) cur[g] = cnt[g*NPART + b];
  __syncthreads();
  int e0 = b*EPB;
  for (int i = t; i < EPB; i += 256) {
    int s = src[e0+i], d = dst[e0+i];
    int g = s / NPG;
    int sl = s - g*NPG, dl = d - g*NPG;
    int pos = atomicAdd(&cur[g], 1);
    part[pos] = (sl << 9) | dl;
  }
}

// K4: per-graph counting sort -> global sorted src list + node metadata
__global__ __launch_bounds__(512) void k_sort(const int* __restrict__ cnt,
    const int* __restrict__ part, unsigned short* __restrict__ sorted_all,
    float* __restrict__ so_all, int* __restrict__ e_end, int* __restrict__ e_deg) {
  __shared__ int indeg[NPG], outdeg[NPG], off[NPG];
  __shared__ int sA[512], sB[512];
  int g = blockIdx.x, t = threadIdx.x;
  int seg0 = cnt[g*NPART];
  int seg1 = (g == N_GRAPHS-1) ? N_EDGES_ : cnt[(g+1)*NPART];
  if (t < NPG) { indeg[t] = 0; outdeg[t] = 0; }
  __syncthreads();
  for (int e = seg0 + t; e < seg1; e += 512) {
    int p = part[e];
    atomicAdd(&indeg[p & 511], 1);
    atomicAdd(&outdeg[p >> 9], 1);
  }
  __syncthreads();
  int v = (t < NPG) ? indeg[t] : 0;
  sA[t] = v; __syncthreads();
  int* cur = sA; int* nxt = sB;
  for (int o = 1; o < 512; o <<= 1) {
    nxt[t] = cur[t] + ((t >= o) ? cur[t-o] : 0);
    __syncthreads();
    int* tmp = cur; cur = nxt; nxt = tmp;
  }
  if (t < NPG) off[t] = cur[t] - v;
  __syncthreads();
  for (int e = seg0 + t; e < seg1; e += 512) {
    int p = part[e];
    int pos = atomicAdd(&off[p & 511], 1);
    sorted_all[seg0 + pos] = (unsigned short)(p >> 9);
  }
  __syncthreads();
  if (t < NPG) {
    so_all[g*NPG + t] = rsqrtf((float)max(outdeg[t], 1));
    e_end[g*NPG + t]  = seg0 + off[t];
    e_deg[g*NPG + t]  = indeg[t];
  }
}

// K5: aggregation — one wave per PADDED node slot; writes bf16 hpreb [g][512][64].
// XCD-aware swizzle: all 128 blocks of a graph land on ONE XCD (blockIdx & 7 ==
// observed round-robin XCD id) so each graph's 128 KB x-slice lives in a single
// L2 instead of being refetched by all 8 (round-7: FETCH 94 MB vs 29 MB unique).
// Wrong mapping assumption costs only speed, never correctness.
__global__ __launch_bounds__(256) void k_agg(const float* __restrict__ x,
    const float* __restrict__ so_all, const int* __restrict__ e_end,
    const int* __restrict__ e_deg, const unsigned short* __restrict__ sorted_all,
    unsigned short* __restrict__ hpreb) {
  int b = blockIdx.x;
  int xcd = b & 7;
  int i_ = b >> 3;                       // 0..3199
  int g = xcd*25 + (i_ >> 7);            // 25 graphs per XCD
  int t = threadIdx.x;
  int nl = ((i_ & 127) << 2) + (t >> 6); // node slot 0..511 within graph
  int npad = g*NPGP + nl;
  int lane = t & 63, q = lane >> 4, ql = lane & 15;
  if (nl >= NPG) {                       // pad row -> zeros
    if (q == 0) {
      ushort4 z; z.x = z.y = z.z = z.w = 0;
      *(ushort4*)(hpreb + (size_t)npad*DIN + ql*4) = z;
    }
    return;
  }
  int n = g*NPG + nl;
  int end = e_end[n], deg = e_deg[n], start = end - deg;
  const float4* xg = ((const float4*)x) + (size_t)g*NPG*16;
  const float* sog = so_all + g*NPG;
  float4 acc = make_float4(0.f, 0.f, 0.f, 0.f);
  for (int i = start + (q << 2); i < end; i += 16) {
    int sj[4];
    #pragma unroll
    for (int j = 0; j < 4; ++j) sj[j] = (i + j < end) ? (int)sorted_all[i+j] : -1;
    #pragma unroll
    for (int j = 0; j < 4; ++j) if (sj[j] >= 0) {
      float sc = sog[sj[j]];
      float4 xv = xg[(size_t)sj[j]*16 + ql];
      acc.x += xv.x*sc; acc.y += xv.y*sc; acc.z += xv.z*sc; acc.w += xv.w*sc;
    }
  }
  acc.x += __shfl_xor(acc.x, 16); acc.y += __shfl_xor(acc.y, 16);
  acc.z += __shfl_xor(acc.z, 16); acc.w += __shfl_xor(acc.w, 16);
  acc.x += __shfl_xor(acc.x, 32); acc.y += __shfl_xor(acc.y, 32);
  acc.z += __shfl_xor(acc.z, 32); acc.w += __shfl_xor(acc.w, 32);
  if (q == 0) {
    float sn = rsqrtf((float)max(deg, 1));
    ushort4 uv;
    uv.x = f2bf(acc.x*sn); uv.y = f2bf(acc.y*sn);
    uv.z = f2bf(acc.z*sn); uv.w = f2bf(acc.w*sn);
    *(ushort4*)(hpreb + (size_t)npad*DIN + ql*4) = uv;
  }
}

// K6: MFMA GCN GEMM + ReLU + mean pool. Block = one graph (512 padded rows).
// w swizzled fp32->bf16 B-fragment layout directly into LDS (k_wprep fused).
// D layout: col = lane&15, row = (lane>>4)*4 + reg. Pad rows masked pre-pool.
__global__ __launch_bounds__(256) void k_gcn(
    const unsigned short* __restrict__ hpreb,
    const float* __restrict__ w_gcn,
    const float* __restrict__ b_gcn,
    float* __restrict__ hg) {
  __shared__ unsigned short wLds[16*64*8];   // 16 KB
  __shared__ float pS[4*DG];
  int t = threadIdx.x, g = blockIdx.x;
  // swizzle: frag f = nt*2 + h; element j of lane l: w[h*32+(l>>4)*8+j][nt*16+(l&15)]
  for (int idx = t; idx < 16*64; idx += 256) {
    int f = idx >> 6, l = idx & 63;
    int h = f & 1, nt = f >> 1;
    int kbase = h*32 + (l >> 4)*8;
    int n = nt*16 + (l & 15);
    #pragma unroll
    for (int j = 0; j < 8; ++j)
      wLds[idx*8 + j] = f2bf(w_gcn[(kbase + j)*DG + n]);
  }
  __syncthreads();
  int w = t >> 6, lane = t & 63;
  int quad = lane >> 4, l15 = lane & 15;
  float bcol[8];
  #pragma unroll
  for (int nt = 0; nt < 8; ++nt) bcol[nt] = b_gcn[nt*16 + l15];
  float psum[8] = {0.f,0.f,0.f,0.f,0.f,0.f,0.f,0.f};
  const unsigned short* hb = hpreb + (size_t)g*NPGP*DIN;
  for (int i = 0; i < 8; ++i) {
    int rt = w + 4*i;
    int row0 = rt*16;
    const short8* aptr = (const short8*)(hb + (size_t)(row0 + l15)*DIN + quad*8);
    short8 a0 = aptr[0];   // k = quad*8 + [0..8)      (K-half 0)
    short8 a1 = aptr[4];   // k = 32 + quad*8 + [0..8) (K-half 1)
    #pragma unroll
    for (int nt = 0; nt < 8; ++nt) {
      short8 b0 = *((const short8*)&wLds[((nt*2+0)*64 + lane)*8]);
      short8 b1 = *((const short8*)&wLds[((nt*2+1)*64 + lane)*8]);
      float4v acc = {0.f, 0.f, 0.f, 0.f};
      acc = __builtin_amdgcn_mfma_f32_16x16x32_bf16(a0, b0, acc, 0, 0, 0);
      acc = __builtin_amdgcn_mfma_f32_16x16x32_bf16(a1, b1, acc, 0, 0, 0);
      #pragma unroll
      for (int r = 0; r < 4; ++r) {
        int node = row0 + quad*4 + r;
        float v = acc[r] + bcol[nt];
        psum[nt] += (node < NPG) ? fmaxf(v, 0.f) : 0.f;
      }
    }
  }
  #pragma unroll
  for (int nt = 0; nt < 8; ++nt) {
    float v = psum[nt];
    v += __shfl_xor(v, 16);
    v += __shfl_xor(v, 32);
    if (lane < 16) pS[w*DG + nt*16 + lane] = v;
  }
  __syncthreads();
  if (t < DG)
    hg[g*DG + t] = (pS[t] + pS[DG+t] + pS[2*DG+t] + pS[3*DG+t]) * (1.0f/NPG);
}

// K7: per-graph input projection
__global__ __launch_bounds__(512) void k_proj(const float* __restrict__ hg,
    const float* __restrict__ w_ih, const float* __restrict__ b_ih,
    float* __restrict__ proj) {
  __shared__ __align__(16) float hS[HL];
  int g = blockIdx.x, r = threadIdx.x;
  if (r < HL) hS[r] = hg[g*HL + r];
  __syncthreads();
  const float4* wr = (const float4*)(w_ih + (size_t)r*HL);
  const float4* hv = (const float4*)hS;
  float acc = b_ih[r];
  #pragma unroll
  for (int k4 = 0; k4 < 32; ++k4) {
    float4 w4 = wr[k4]; float4 h4 = hv[k4];
    acc += w4.x*h4.x + w4.y*h4.y + w4.z*h4.z + w4.w*h4.w;
  }
  proj[(size_t)g*G4 + r] = acc;
}

// K8: LSTM, block per window, thread per gate-row
__global__ __launch_bounds__(512) void k_lstm(const float* __restrict__ proj,
    const float* __restrict__ w_hh, const float* __restrict__ b_hh,
    const float* __restrict__ w_fc, const float* __restrict__ b_fc,
    float* __restrict__ out) {
  __shared__ __align__(16) float hS[HL];
  __shared__ float gS[G4];
  int b = blockIdx.x, r = threadIdx.x;
  float wreg[HL];
  const float4* wr = (const float4*)(w_hh + (size_t)r*HL);
  #pragma unroll
  for (int k4 = 0; k4 < 32; ++k4) {
    float4 w4 = wr[k4];
    wreg[k4*4+0]=w4.x; wreg[k4*4+1]=w4.y; wreg[k4*4+2]=w4.z; wreg[k4*4+3]=w4.w;
  }
  float bh = b_hh[r];
  float c = 0.0f;
  if (r < HL) hS[r] = 0.0f;
  __syncthreads();
  for (int l = 0; l < SEQ; ++l) {
    float acc = proj[(size_t)(b+l)*G4 + r] + bh;
    const float4* hv = (const float4*)hS;
    #pragma unroll
    for (int k4 = 0; k4 < 32; ++k4) {
      float4 h4 = hv[k4];
      acc += h4.x*wreg[k4*4] + h4.y*wreg[k4*4+1] + h4.z*wreg[k4*4+2] + h4.w*wreg[k4*4+3];
    }
    gS[r] = acc;
    __syncthreads();
    if (r < HL) {
      float gi = sigmoidf_(gS[r]);
      float gf = sigmoidf_(gS[HL + r]);
      float gg = tanhf(gS[2*HL + r]);
      float go = sigmoidf_(gS[3*HL + r]);
      c = gf*c + gi*gg;
      hS[r] = go * tanhf(c);
    }
    __syncthreads();
  }
  if (r < 64) {
    float s = hS[r]*w_fc[r] + hS[r+64]*w_fc[r+64];
    #pragma unroll
    for (int off = 32; off > 0; off >>= 1) s += __shfl_down(s, off);
    if (r == 0) out[b] = s + b_fc[0];
  }
}

extern "C" void kernel_launch(void* const* d_in, const int* in_sizes, int n_in,
                              void* d_out, int out_size, void* d_ws, size_t ws_size,
                              hipStream_t stream) {
  const float* x     = (const float*)d_in[0];
  const int*   src   = (const int*)d_in[1];
  const int*   dst   = (const int*)d_in[2];
  const float* w_gcn = (const float*)d_in[4];
  const float* b_gcn = (const float*)d_in[5];
  const float* w_ih  = (const float*)d_in[6];
  const float* w_hh  = (const float*)d_in[7];
  const float* b_ih  = (const float*)d_in[8];
  const float* b_hh  = (const float*)d_in[9];
  const float* w_fc  = (const float*)d_in[10];
  const float* b_fc  = (const float*)d_in[11];
  float* out = (float*)d_out;

  char* ws = (char*)d_ws;
  size_t off = 0;
  auto alloc = [&](size_t bytes) -> void* {
    void* p = ws + off; off += (bytes + 255) & ~(size_t)255; return p;
  };
  int* cnt     = (int*)alloc((size_t)NCNT*4);
  int* part    = (int*)alloc((size_t)N_EDGES_*4);
  unsigned short* sorted_all = (unsigned short*)alloc((size_t)N_EDGES_*2);
  float* so_all = (float*)alloc((size_t)N_NODES_*4);
  int* e_end   = (int*)alloc((size_t)N_NODES_*4);
  int* e_deg   = (int*)alloc((size_t)N_NODES_*4);
  unsigned short* hpreb = (unsigned short*)alloc((size_t)N_GRAPHS*NPGP*DIN*2);
  float* hg    = (float*)alloc((size_t)N_GRAPHS*DG*4);
  float* proj  = (float*)alloc((size_t)N_GRAPHS*G4*4);
  (void)ws_size; (void)in_sizes; (void)n_in; (void)out_size;

  k_count<<<NPART, 256, 0, stream>>>(src, cnt);
  k_pscan<<<1, 1024, 0, stream>>>(cnt);
  k_part<<<NPART, 256, 0, stream>>>(src, dst, cnt, part);
  k_sort<<<N_GRAPHS, 512, 0, stream>>>(cnt, part, sorted_all, so_all, e_end, e_deg);
  k_agg<<<(N_GRAPHS*NPGP)/4, 256, 0, stream>>>(x, so_all, e_end, e_deg, sorted_all, hpreb);
  k_gcn<<<N_GRAPHS, 256, 0, stream>>>(hpreb, w_gcn, b_gcn, hg);
  k_proj<<<N_GRAPHS, 512, 0, stream>>>(hg, w_ih, b_ih, proj);
  k_lstm<<<BWIN, 512, 0, stream>>>(proj, w_hh, b_hh, w_fc, b_fc, out);
}

// Round 9
// 255.565 us; speedup vs baseline: 1.6196x; 1.0789x over previous
//
#include <hip/hip_runtime.h>
#include <hip/hip_bf16.h>

#define N_GRAPHS 200
#define NPG      500
#define NPGP     512                   // padded nodes per graph (MFMA tiles)
#define N_NODES_ 100000
#define N_EDGES_ 1600000
#define DIN      64
#define DG       128
#define SEQ      20
#define HL       128
#define G4       512
#define BWIN     (N_GRAPHS - SEQ + 1)  // 181
#define NPART    256
#define EPB      (N_EDGES_/NPART)      // 6250
#define NCNT     (N_GRAPHS*NPART)      // 51200

typedef __attribute__((ext_vector_type(8))) short short8;
typedef __attribute__((ext_vector_type(4))) float float4v;

__device__ __forceinline__ float sigmoidf_(float v){ return 1.0f/(1.0f+expf(-v)); }

// fp32 -> bf16 round-to-nearest-even
__device__ __forceinline__ unsigned short f2bf(float f) {
  unsigned int u = __float_as_uint(f);
  u += 0x7fffu + ((u >> 16) & 1u);
  return (unsigned short)(u >> 16);
}

// K1: per-(block,graph) edge counts via LDS histogram (no global atomics)
__global__ __launch_bounds__(256) void k_count(const int* __restrict__ src,
                                               int* __restrict__ cnt) {
  __shared__ int bins[N_GRAPHS];
  int b = blockIdx.x, t = threadIdx.x;
  for (int i = t; i < N_GRAPHS; i += 256) bins[i] = 0;
  __syncthreads();
  int e0 = b*EPB;
  for (int i = t; i < EPB; i += 256) atomicAdd(&bins[src[e0+i]/NPG], 1);
  __syncthreads();
  for (int g = t; g < N_GRAPHS; g += 256) cnt[g*NPART + b] = bins[g];
}

// K2: exclusive scan of 51200 counts; streaming two-pass (no big reg array)
__global__ __launch_bounds__(1024) void k_pscan(int* __restrict__ cnt) {
  __shared__ int sA[1024], sB[1024];
  int t = threadIdx.x;
  int base = t*50;
  int s = 0;
  for (int j = 0; j < 50; ++j) s += cnt[base+j];
  sA[t] = s; __syncthreads();
  int* cur = sA; int* nxt = sB;
  for (int off = 1; off < 1024; off <<= 1) {
    nxt[t] = cur[t] + ((t >= off) ? cur[t-off] : 0);
    __syncthreads();
    int* tmp = cur; cur = nxt; nxt = tmp;
  }
  int run = cur[t] - s;
  for (int j = 0; j < 50; ++j) {
    int v = cnt[base+j];
    cnt[base+j] = run;
    run += v;
  }
}

// K3: deterministic partition by graph; packed (src_local<<9 | dst_local)
__global__ __launch_bounds__(256) void k_part(const int* __restrict__ src,
                                              const int* __restrict__ dst,
                                              const int* __restrict__ cnt,
                                              int* __restrict__ part) {
  __shared__ int cur[N_GRAPHS];
  int b = blockIdx.x, t = threadIdx.x;
  for (int g = t; g < N_GRAPHS; g += 256) cur[g] = cnt[g*NPART + b];
  __syncthreads();
  int e0 = b*EPB;
  for (int i = t; i < EPB; i += 256) {
    int s = src[e0+i], d = dst[e0+i];
    int g = s / NPG;
    int sl = s - g*NPG, dl = d - g*NPG;
    int pos = atomicAdd(&cur[g], 1);
    part[pos] = (sl << 9) | dl;
  }
}

// K4: per-graph counting sort -> global sorted src list + node metadata
__global__ __launch_bounds__(512) void k_sort(const int* __restrict__ cnt,
    const int* __restrict__ part, unsigned short* __restrict__ sorted_all,
    float* __restrict__ so_all, int* __restrict__ e_end, int* __restrict__ e_deg) {
  __shared__ int indeg[NPG], outdeg[NPG], off[NPG];
  __shared__ int sA[512], sB[512];
  int g = blockIdx.x, t = threadIdx.x;
  int seg0 = cnt[g*NPART];
  int seg1 = (g == N_GRAPHS-1) ? N_EDGES_ : cnt[(g+1)*NPART];
  if (t < NPG) { indeg[t] = 0; outdeg[t] = 0; }
  __syncthreads();
  for (int e = seg0 + t; e < seg1; e += 512) {
    int p = part[e];
    atomicAdd(&indeg[p & 511], 1);
    atomicAdd(&outdeg[p >> 9], 1);
  }
  __syncthreads();
  int v = (t < NPG) ? indeg[t] : 0;
  sA[t] = v; __syncthreads();
  int* cur = sA; int* nxt = sB;
  for (int o = 1; o < 512; o <<= 1) {
    nxt[t] = cur[t] + ((t >= o) ? cur[t-o] : 0);
    __syncthreads();
    int* tmp = cur; cur = nxt; nxt = tmp;
  }
  if (t < NPG) off[t] = cur[t] - v;
  __syncthreads();
  for (int e = seg0 + t; e < seg1; e += 512) {
    int p = part[e];
    int pos = atomicAdd(&off[p & 511], 1);
    sorted_all[seg0 + pos] = (unsigned short)(p >> 9);
  }
  __syncthreads();
  if (t < NPG) {
    so_all[g*NPG + t] = rsqrtf((float)max(outdeg[t], 1));
    e_end[g*NPG + t]  = seg0 + off[t];
    e_deg[g*NPG + t]  = indeg[t];
  }
}

// K5a: pre-scaled bf16 source rows: xsb[n][k] = bf16(x[n][k] * so[n]).
// Removes the per-edge so gather/mul and halves per-edge gather bytes.
__global__ __launch_bounds__(256) void k_xprep(const float* __restrict__ x,
    const float* __restrict__ so_all, ushort4* __restrict__ xsb) {
  __shared__ float soS[NPG];
  int g = blockIdx.x, t = threadIdx.x;
  for (int i = t; i < NPG; i += 256) soS[i] = so_all[g*NPG + i];
  __syncthreads();
  const float4* xg = ((const float4*)x) + (size_t)g*8000;   // 500*16
  ushort4* og = xsb + (size_t)g*8000;
  for (int i = t; i < 8000; i += 256) {
    float4 v = xg[i];
    float s = soS[i >> 4];
    ushort4 u;
    u.x = f2bf(v.x*s); u.y = f2bf(v.y*s); u.z = f2bf(v.z*s); u.w = f2bf(v.w*s);
    og[i] = u;
  }
}

// K5b: aggregation v3 — wave per node slot; 8 lanes per edge (int4 = 8 bf16),
// 2-edge unroll per group. Packed-bf16 accumulate (exact): the high ushort of
// each dword IS a fp32 (bf16 = truncated fp32), low ushort via <<16.
// XCD swizzle: g % 8 == xcd (matches k_sort/k_xprep natural round-robin).
__global__ __launch_bounds__(256) void k_agg(const int4* __restrict__ xsb,
    const int* __restrict__ e_end, const int* __restrict__ e_deg,
    const unsigned short* __restrict__ sorted_all,
    unsigned short* __restrict__ hpreb) {
  int b = blockIdx.x;
  int xcd = b & 7;
  int i_ = b >> 3;                       // 0..3199
  int g = (i_ >> 7)*8 + xcd;             // g % 8 == xcd
  int t = threadIdx.x;
  int nl = ((i_ & 127) << 2) + (t >> 6); // node slot 0..511 within graph
  int npad = g*NPGP + nl;
  int lane = t & 63, g8 = lane >> 3, fl = lane & 7;
  if (nl >= NPG) {                       // pad rows -> zeros
    if (g8 == 0) {
      int4 z = make_int4(0,0,0,0);
      ((int4*)hpreb)[(size_t)npad*8 + fl] = z;
    }
    return;
  }
  int n = g*NPG + nl;
  int end = e_end[n], deg = e_deg[n], start = end - deg;
  const int4* xg = xsb + (size_t)g*4000;      // 500 rows * 8 int4
  float aHi[4] = {0.f,0.f,0.f,0.f};
  float aLo[4] = {0.f,0.f,0.f,0.f};
  for (int i = start + (g8 << 1); i < end; i += 16) {
    int s0 = (int)sorted_all[i];
    int4 v = xg[s0*8 + fl];
    aHi[0] += __uint_as_float((unsigned)v.x & 0xffff0000u);
    aLo[0] += __uint_as_float((unsigned)v.x << 16);
    aHi[1] += __uint_as_float((unsigned)v.y & 0xffff0000u);
    aLo[1] += __uint_as_float((unsigned)v.y << 16);
    aHi[2] += __uint_as_float((unsigned)v.z & 0xffff0000u);
    aLo[2] += __uint_as_float((unsigned)v.z << 16);
    aHi[3] += __uint_as_float((unsigned)v.w & 0xffff0000u);
    aLo[3] += __uint_as_float((unsigned)v.w << 16);
    if (i + 1 < end) {
      int s1 = (int)sorted_all[i+1];
      int4 w = xg[s1*8 + fl];
      aHi[0] += __uint_as_float((unsigned)w.x & 0xffff0000u);
      aLo[0] += __uint_as_float((unsigned)w.x << 16);
      aHi[1] += __uint_as_float((unsigned)w.y & 0xffff0000u);
      aLo[1] += __uint_as_float((unsigned)w.y << 16);
      aHi[2] += __uint_as_float((unsigned)w.z & 0xffff0000u);
      aLo[2] += __uint_as_float((unsigned)w.z << 16);
      aHi[3] += __uint_as_float((unsigned)w.w & 0xffff0000u);
      aLo[3] += __uint_as_float((unsigned)w.w << 16);
    }
  }
  #pragma unroll
  for (int m = 8; m < 64; m <<= 1) {
    #pragma unroll
    for (int d = 0; d < 4; ++d) {
      aHi[d] += __shfl_xor(aHi[d], m);
      aLo[d] += __shfl_xor(aLo[d], m);
    }
  }
  if (g8 == 0) {
    float sn = rsqrtf((float)max(deg, 1));
    int4 outv;
    outv.x = (int)(((unsigned)f2bf(aLo[0]*sn)) | ((unsigned)f2bf(aHi[0]*sn) << 16));
    outv.y = (int)(((unsigned)f2bf(aLo[1]*sn)) | ((unsigned)f2bf(aHi[1]*sn) << 16));
    outv.z = (int)(((unsigned)f2bf(aLo[2]*sn)) | ((unsigned)f2bf(aHi[2]*sn) << 16));
    outv.w = (int)(((unsigned)f2bf(aLo[3]*sn)) | ((unsigned)f2bf(aHi[3]*sn) << 16));
    ((int4*)hpreb)[(size_t)npad*8 + fl] = outv;
  }
}

// K6: MFMA GCN GEMM + ReLU + mean pool. Block = one graph (512 padded rows).
__global__ __launch_bounds__(256) void k_gcn(
    const unsigned short* __restrict__ hpreb,
    const float* __restrict__ w_gcn,
    const float* __restrict__ b_gcn,
    float* __restrict__ hg) {
  __shared__ unsigned short wLds[16*64*8];   // 16 KB
  __shared__ float pS[4*DG];
  int t = threadIdx.x, g = blockIdx.x;
  for (int idx = t; idx < 16*64; idx += 256) {
    int f = idx >> 6, l = idx & 63;
    int h = f & 1, nt = f >> 1;
    int kbase = h*32 + (l >> 4)*8;
    int n = nt*16 + (l & 15);
    #pragma unroll
    for (int j = 0; j < 8; ++j)
      wLds[idx*8 + j] = f2bf(w_gcn[(kbase + j)*DG + n]);
  }
  __syncthreads();
  int w = t >> 6, lane = t & 63;
  int quad = lane >> 4, l15 = lane & 15;
  float bcol[8];
  #pragma unroll
  for (int nt = 0; nt < 8; ++nt) bcol[nt] = b_gcn[nt*16 + l15];
  float psum[8] = {0.f,0.f,0.f,0.f,0.f,0.f,0.f,0.f};
  const unsigned short* hb = hpreb + (size_t)g*NPGP*DIN;
  for (int i = 0; i < 8; ++i) {
    int rt = w + 4*i;
    int row0 = rt*16;
    const short8* aptr = (const short8*)(hb + (size_t)(row0 + l15)*DIN + quad*8);
    short8 a0 = aptr[0];
    short8 a1 = aptr[4];
    #pragma unroll
    for (int nt = 0; nt < 8; ++nt) {
      short8 b0 = *((const short8*)&wLds[((nt*2+0)*64 + lane)*8]);
      short8 b1 = *((const short8*)&wLds[((nt*2+1)*64 + lane)*8]);
      float4v acc = {0.f, 0.f, 0.f, 0.f};
      acc = __builtin_amdgcn_mfma_f32_16x16x32_bf16(a0, b0, acc, 0, 0, 0);
      acc = __builtin_amdgcn_mfma_f32_16x16x32_bf16(a1, b1, acc, 0, 0, 0);
      #pragma unroll
      for (int r = 0; r < 4; ++r) {
        int node = row0 + quad*4 + r;
        float v = acc[r] + bcol[nt];
        psum[nt] += (node < NPG) ? fmaxf(v, 0.f) : 0.f;
      }
    }
  }
  #pragma unroll
  for (int nt = 0; nt < 8; ++nt) {
    float v = psum[nt];
    v += __shfl_xor(v, 16);
    v += __shfl_xor(v, 32);
    if (lane < 16) pS[w*DG + nt*16 + lane] = v;
  }
  __syncthreads();
  if (t < DG)
    hg[g*DG + t] = (pS[t] + pS[DG+t] + pS[2*DG+t] + pS[3*DG+t]) * (1.0f/NPG);
}

// K7: per-graph input projection
__global__ __launch_bounds__(512) void k_proj(const float* __restrict__ hg,
    const float* __restrict__ w_ih, const float* __restrict__ b_ih,
    float* __restrict__ proj) {
  __shared__ __align__(16) float hS[HL];
  int g = blockIdx.x, r = threadIdx.x;
  if (r < HL) hS[r] = hg[g*HL + r];
  __syncthreads();
  const float4* wr = (const float4*)(w_ih + (size_t)r*HL);
  const float4* hv = (const float4*)hS;
  float acc = b_ih[r];
  #pragma unroll
  for (int k4 = 0; k4 < 32; ++k4) {
    float4 w4 = wr[k4]; float4 h4 = hv[k4];
    acc += w4.x*h4.x + w4.y*h4.y + w4.z*h4.z + w4.w*h4.w;
  }
  proj[(size_t)g*G4 + r] = acc;
}

// K8: LSTM, block per window, thread per gate-row, w_hh row in VGPRs.
// (512,2): 256-VGPR budget so wreg[128] stays resident.
__global__ __launch_bounds__(512, 2) void k_lstm(const float* __restrict__ proj,
    const float* __restrict__ w_hh, const float* __restrict__ b_hh,
    const float* __restrict__ w_fc, const float* __restrict__ b_fc,
    float* __restrict__ out) {
  __shared__ __align__(16) float hS[HL];
  __shared__ float gS[G4];
  int b = blockIdx.x, r = threadIdx.x;
  float wreg[HL];
  const float4* wr = (const float4*)(w_hh + (size_t)r*HL);
  #pragma unroll
  for (int k4 = 0; k4 < 32; ++k4) {
    float4 w4 = wr[k4];
    wreg[k4*4+0]=w4.x; wreg[k4*4+1]=w4.y; wreg[k4*4+2]=w4.z; wreg[k4*4+3]=w4.w;
  }
  float bh = b_hh[r];
  float c = 0.0f;
  if (r < HL) hS[r] = 0.0f;
  __syncthreads();
  for (int l = 0; l < SEQ; ++l) {
    float acc = proj[(size_t)(b+l)*G4 + r] + bh;
    const float4* hv = (const float4*)hS;
    #pragma unroll
    for (int k4 = 0; k4 < 32; ++k4) {
      float4 h4 = hv[k4];
      acc += h4.x*wreg[k4*4] + h4.y*wreg[k4*4+1] + h4.z*wreg[k4*4+2] + h4.w*wreg[k4*4+3];
    }
    gS[r] = acc;
    __syncthreads();
    if (r < HL) {
      float gi = sigmoidf_(gS[r]);
      float gf = sigmoidf_(gS[HL + r]);
      float gg = tanhf(gS[2*HL + r]);
      float go = sigmoidf_(gS[3*HL + r]);
      c = gf*c + gi*gg;
      hS[r] = go * tanhf(c);
    }
    __syncthreads();
  }
  if (r < 64) {
    float s = hS[r]*w_fc[r] + hS[r+64]*w_fc[r+64];
    #pragma unroll
    for (int off = 32; off > 0; off >>= 1) s += __shfl_down(s, off);
    if (r == 0) out[b] = s + b_fc[0];
  }
}

extern "C" void kernel_launch(void* const* d_in, const int* in_sizes, int n_in,
                              void* d_out, int out_size, void* d_ws, size_t ws_size,
                              hipStream_t stream) {
  const float* x     = (const float*)d_in[0];
  const int*   src   = (const int*)d_in[1];
  const int*   dst   = (const int*)d_in[2];
  const float* w_gcn = (const float*)d_in[4];
  const float* b_gcn = (const float*)d_in[5];
  const float* w_ih  = (const float*)d_in[6];
  const float* w_hh  = (const float*)d_in[7];
  const float* b_ih  = (const float*)d_in[8];
  const float* b_hh  = (const float*)d_in[9];
  const float* w_fc  = (const float*)d_in[10];
  const float* b_fc  = (const float*)d_in[11];
  float* out = (float*)d_out;

  char* ws = (char*)d_ws;
  size_t off = 0;
  auto alloc = [&](size_t bytes) -> void* {
    void* p = ws + off; off += (bytes + 255) & ~(size_t)255; return p;
  };
  int* cnt     = (int*)alloc((size_t)NCNT*4);
  int* part    = (int*)alloc((size_t)N_EDGES_*4);
  unsigned short* sorted_all = (unsigned short*)alloc((size_t)N_EDGES_*2);
  float* so_all = (float*)alloc((size_t)N_NODES_*4);
  int* e_end   = (int*)alloc((size_t)N_NODES_*4);
  int* e_deg   = (int*)alloc((size_t)N_NODES_*4);
  ushort4* xsb = (ushort4*)alloc((size_t)N_NODES_*DIN*2);
  unsigned short* hpreb = (unsigned short*)alloc((size_t)N_GRAPHS*NPGP*DIN*2);
  float* hg    = (float*)alloc((size_t)N_GRAPHS*DG*4);
  float* proj  = (float*)alloc((size_t)N_GRAPHS*G4*4);
  (void)ws_size; (void)in_sizes; (void)n_in; (void)out_size;

  k_count<<<NPART, 256, 0, stream>>>(src, cnt);
  k_pscan<<<1, 1024, 0, stream>>>(cnt);
  k_part<<<NPART, 256, 0, stream>>>(src, dst, cnt, part);
  k_sort<<<N_GRAPHS, 512, 0, stream>>>(cnt, part, sorted_all, so_all, e_end, e_deg);
  k_xprep<<<N_GRAPHS, 256, 0, stream>>>(x, so_all, xsb);
  k_agg<<<(N_GRAPHS*NPGP)/4, 256, 0, stream>>>((const int4*)xsb, e_end, e_deg, sorted_all, hpreb);
  k_gcn<<<N_GRAPHS, 256, 0, stream>>>(hpreb, w_gcn, b_gcn, hg);
  k_proj<<<N_GRAPHS, 512, 0, stream>>>(hg, w_ih, b_ih, proj);
  k_lstm<<<BWIN, 512, 0, stream>>>(proj, w_hh, b_hh, w_fc, b_fc, out);
}

// Round 10
// 245.253 us; speedup vs baseline: 1.6877x; 1.0420x over previous
//
#include <hip/hip_runtime.h>
#include <hip/hip_bf16.h>

#define N_GRAPHS 200
#define NPG      500
#define NPGP     512                   // padded nodes per graph (MFMA tiles)
#define N_NODES_ 100000
#define N_EDGES_ 1600000
#define DIN      64
#define DG       128
#define SEQ      20
#define HL       128
#define G4       512
#define BWIN     (N_GRAPHS - SEQ + 1)  // 181
#define NPART    256
#define EPB      (N_EDGES_/NPART)      // 6250
#define NCNT     (N_GRAPHS*NPART)      // 51200

typedef __attribute__((ext_vector_type(8))) short short8;
typedef __attribute__((ext_vector_type(4))) float float4v;
typedef __attribute__((ext_vector_type(2))) _Float16 half2v;

__device__ __forceinline__ float sigmoidf_(float v){ return 1.0f/(1.0f+expf(-v)); }

// fp32 -> bf16 round-to-nearest-even
__device__ __forceinline__ unsigned short f2bf(float f) {
  unsigned int u = __float_as_uint(f);
  u += 0x7fffu + ((u >> 16) & 1u);
  return (unsigned short)(u >> 16);
}

__device__ __forceinline__ float h2dot(half2v a, half2v b, float c) {
#if __has_builtin(__builtin_amdgcn_fdot2)
  return __builtin_amdgcn_fdot2(a, b, c, false);
#else
  return c + (float)a.x*(float)b.x + (float)a.y*(float)b.y;
#endif
}

// K1: per-(block,graph) edge counts via LDS histogram (no global atomics)
__global__ __launch_bounds__(256) void k_count(const int* __restrict__ src,
                                               int* __restrict__ cnt) {
  __shared__ int bins[N_GRAPHS];
  int b = blockIdx.x, t = threadIdx.x;
  for (int i = t; i < N_GRAPHS; i += 256) bins[i] = 0;
  __syncthreads();
  int e0 = b*EPB;
  for (int i = t; i < EPB; i += 256) atomicAdd(&bins[src[e0+i]/NPG], 1);
  __syncthreads();
  for (int g = t; g < N_GRAPHS; g += 256) cnt[g*NPART + b] = bins[g];
}

// K2: exclusive scan of 51200 counts; streaming two-pass (no big reg array)
__global__ __launch_bounds__(1024) void k_pscan(int* __restrict__ cnt) {
  __shared__ int sA[1024], sB[1024];
  int t = threadIdx.x;
  int base = t*50;
  int s = 0;
  for (int j = 0; j < 50; ++j) s += cnt[base+j];
  sA[t] = s; __syncthreads();
  int* cur = sA; int* nxt = sB;
  for (int off = 1; off < 1024; off <<= 1) {
    nxt[t] = cur[t] + ((t >= off) ? cur[t-off] : 0);
    __syncthreads();
    int* tmp = cur; cur = nxt; nxt = tmp;
  }
  int run = cur[t] - s;
  for (int j = 0; j < 50; ++j) {
    int v = cnt[base+j];
    cnt[base+j] = run;
    run += v;
  }
}

// K3: deterministic partition by graph; packed (src_local<<9 | dst_local)
__global__ __launch_bounds__(256) void k_part(const int* __restrict__ src,
                                              const int* __restrict__ dst,
                                              const int* __restrict__ cnt,
                                              int* __restrict__ part) {
  __shared__ int cur[N_GRAPHS];
  int b = blockIdx.x, t = threadIdx.x;
  for (int g = t; g < N_GRAPHS; g += 256) cur[g] = cnt[g*NPART + b];
  __syncthreads();
  int e0 = b*EPB;
  for (int i = t; i < EPB; i += 256) {
    int s = src[e0+i], d = dst[e0+i];
    int g = s / NPG;
    int sl = s - g*NPG, dl = d - g*NPG;
    int pos = atomicAdd(&cur[g], 1);
    part[pos] = (sl << 9) | dl;
  }
}

// K4: per-graph counting sort -> global sorted src list + node metadata
__global__ __launch_bounds__(512) void k_sort(const int* __restrict__ cnt,
    const int* __restrict__ part, unsigned short* __restrict__ sorted_all,
    float* __restrict__ so_all, int* __restrict__ e_end, int* __restrict__ e_deg) {
  __shared__ int indeg[NPG], outdeg[NPG], off[NPG];
  __shared__ int sA[512], sB[512];
  int g = blockIdx.x, t = threadIdx.x;
  int seg0 = cnt[g*NPART];
  int seg1 = (g == N_GRAPHS-1) ? N_EDGES_ : cnt[(g+1)*NPART];
  if (t < NPG) { indeg[t] = 0; outdeg[t] = 0; }
  __syncthreads();
  for (int e = seg0 + t; e < seg1; e += 512) {
    int p = part[e];
    atomicAdd(&indeg[p & 511], 1);
    atomicAdd(&outdeg[p >> 9], 1);
  }
  __syncthreads();
  int v = (t < NPG) ? indeg[t] : 0;
  sA[t] = v; __syncthreads();
  int* cur = sA; int* nxt = sB;
  for (int o = 1; o < 512; o <<= 1) {
    nxt[t] = cur[t] + ((t >= o) ? cur[t-o] : 0);
    __syncthreads();
    int* tmp = cur; cur = nxt; nxt = tmp;
  }
  if (t < NPG) off[t] = cur[t] - v;
  __syncthreads();
  for (int e = seg0 + t; e < seg1; e += 512) {
    int p = part[e];
    int pos = atomicAdd(&off[p & 511], 1);
    sorted_all[seg0 + pos] = (unsigned short)(p >> 9);
  }
  __syncthreads();
  if (t < NPG) {
    so_all[g*NPG + t] = rsqrtf((float)max(outdeg[t], 1));
    e_end[g*NPG + t]  = seg0 + off[t];
    e_deg[g*NPG + t]  = indeg[t];
  }
}

// K5a: pre-scaled bf16 source rows: xsb[n][k] = bf16(x[n][k] * so[n]).
__global__ __launch_bounds__(256) void k_xprep(const float* __restrict__ x,
    const float* __restrict__ so_all, ushort4* __restrict__ xsb) {
  __shared__ float soS[NPG];
  int g = blockIdx.x, t = threadIdx.x;
  for (int i = t; i < NPG; i += 256) soS[i] = so_all[g*NPG + i];
  __syncthreads();
  const float4* xg = ((const float4*)x) + (size_t)g*8000;   // 500*16
  ushort4* og = xsb + (size_t)g*8000;
  for (int i = t; i < 8000; i += 256) {
    float4 v = xg[i];
    float s = soS[i >> 4];
    ushort4 u;
    u.x = f2bf(v.x*s); u.y = f2bf(v.y*s); u.z = f2bf(v.z*s); u.w = f2bf(v.w*s);
    og[i] = u;
  }
}

// K5b: aggregation v3 — wave per node slot; 8 lanes per edge (int4 = 8 bf16),
// packed-bf16 accumulate (exact). XCD swizzle: g % 8 == xcd.
__global__ __launch_bounds__(256) void k_agg(const int4* __restrict__ xsb,
    const int* __restrict__ e_end, const int* __restrict__ e_deg,
    const unsigned short* __restrict__ sorted_all,
    unsigned short* __restrict__ hpreb) {
  int b = blockIdx.x;
  int xcd = b & 7;
  int i_ = b >> 3;                       // 0..3199
  int g = (i_ >> 7)*8 + xcd;             // g % 8 == xcd
  int t = threadIdx.x;
  int nl = ((i_ & 127) << 2) + (t >> 6); // node slot 0..511 within graph
  int npad = g*NPGP + nl;
  int lane = t & 63, g8 = lane >> 3, fl = lane & 7;
  if (nl >= NPG) {                       // pad rows -> zeros
    if (g8 == 0) {
      int4 z = make_int4(0,0,0,0);
      ((int4*)hpreb)[(size_t)npad*8 + fl] = z;
    }
    return;
  }
  int n = g*NPG + nl;
  int end = e_end[n], deg = e_deg[n], start = end - deg;
  const int4* xg = xsb + (size_t)g*4000;      // 500 rows * 8 int4
  float aHi[4] = {0.f,0.f,0.f,0.f};
  float aLo[4] = {0.f,0.f,0.f,0.f};
  for (int i = start + (g8 << 1); i < end; i += 16) {
    int s0 = (int)sorted_all[i];
    int4 v = xg[s0*8 + fl];
    aHi[0] += __uint_as_float((unsigned)v.x & 0xffff0000u);
    aLo[0] += __uint_as_float((unsigned)v.x << 16);
    aHi[1] += __uint_as_float((unsigned)v.y & 0xffff0000u);
    aLo[1] += __uint_as_float((unsigned)v.y << 16);
    aHi[2] += __uint_as_float((unsigned)v.z & 0xffff0000u);
    aLo[2] += __uint_as_float((unsigned)v.z << 16);
    aHi[3] += __uint_as_float((unsigned)v.w & 0xffff0000u);
    aLo[3] += __uint_as_float((unsigned)v.w << 16);
    if (i + 1 < end) {
      int s1 = (int)sorted_all[i+1];
      int4 w = xg[s1*8 + fl];
      aHi[0] += __uint_as_float((unsigned)w.x & 0xffff0000u);
      aLo[0] += __uint_as_float((unsigned)w.x << 16);
      aHi[1] += __uint_as_float((unsigned)w.y & 0xffff0000u);
      aLo[1] += __uint_as_float((unsigned)w.y << 16);
      aHi[2] += __uint_as_float((unsigned)w.z & 0xffff0000u);
      aLo[2] += __uint_as_float((unsigned)w.z << 16);
      aHi[3] += __uint_as_float((unsigned)w.w & 0xffff0000u);
      aLo[3] += __uint_as_float((unsigned)w.w << 16);
    }
  }
  #pragma unroll
  for (int m = 8; m < 64; m <<= 1) {
    #pragma unroll
    for (int d = 0; d < 4; ++d) {
      aHi[d] += __shfl_xor(aHi[d], m);
      aLo[d] += __shfl_xor(aLo[d], m);
    }
  }
  if (g8 == 0) {
    float sn = rsqrtf((float)max(deg, 1));
    int4 outv;
    outv.x = (int)(((unsigned)f2bf(aLo[0]*sn)) | ((unsigned)f2bf(aHi[0]*sn) << 16));
    outv.y = (int)(((unsigned)f2bf(aLo[1]*sn)) | ((unsigned)f2bf(aHi[1]*sn) << 16));
    outv.z = (int)(((unsigned)f2bf(aLo[2]*sn)) | ((unsigned)f2bf(aHi[2]*sn) << 16));
    outv.w = (int)(((unsigned)f2bf(aLo[3]*sn)) | ((unsigned)f2bf(aHi[3]*sn) << 16));
    ((int4*)hpreb)[(size_t)npad*8 + fl] = outv;
  }
}

// K6: MFMA GCN GEMM + ReLU + mean pool. Block = one graph (512 padded rows).
__global__ __launch_bounds__(256) void k_gcn(
    const unsigned short* __restrict__ hpreb,
    const float* __restrict__ w_gcn,
    const float* __restrict__ b_gcn,
    float* __restrict__ hg) {
  __shared__ unsigned short wLds[16*64*8];   // 16 KB
  __shared__ float pS[4*DG];
  int t = threadIdx.x, g = blockIdx.x;
  for (int idx = t; idx < 16*64; idx += 256) {
    int f = idx >> 6, l = idx & 63;
    int h = f & 1, nt = f >> 1;
    int kbase = h*32 + (l >> 4)*8;
    int n = nt*16 + (l & 15);
    #pragma unroll
    for (int j = 0; j < 8; ++j)
      wLds[idx*8 + j] = f2bf(w_gcn[(kbase + j)*DG + n]);
  }
  __syncthreads();
  int w = t >> 6, lane = t & 63;
  int quad = lane >> 4, l15 = lane & 15;
  float bcol[8];
  #pragma unroll
  for (int nt = 0; nt < 8; ++nt) bcol[nt] = b_gcn[nt*16 + l15];
  float psum[8] = {0.f,0.f,0.f,0.f,0.f,0.f,0.f,0.f};
  const unsigned short* hb = hpreb + (size_t)g*NPGP*DIN;
  for (int i = 0; i < 8; ++i) {
    int rt = w + 4*i;
    int row0 = rt*16;
    const short8* aptr = (const short8*)(hb + (size_t)(row0 + l15)*DIN + quad*8);
    short8 a0 = aptr[0];
    short8 a1 = aptr[4];
    #pragma unroll
    for (int nt = 0; nt < 8; ++nt) {
      short8 b0 = *((const short8*)&wLds[((nt*2+0)*64 + lane)*8]);
      short8 b1 = *((const short8*)&wLds[((nt*2+1)*64 + lane)*8]);
      float4v acc = {0.f, 0.f, 0.f, 0.f};
      acc = __builtin_amdgcn_mfma_f32_16x16x32_bf16(a0, b0, acc, 0, 0, 0);
      acc = __builtin_amdgcn_mfma_f32_16x16x32_bf16(a1, b1, acc, 0, 0, 0);
      #pragma unroll
      for (int r = 0; r < 4; ++r) {
        int node = row0 + quad*4 + r;
        float v = acc[r] + bcol[nt];
        psum[nt] += (node < NPG) ? fmaxf(v, 0.f) : 0.f;
      }
    }
  }
  #pragma unroll
  for (int nt = 0; nt < 8; ++nt) {
    float v = psum[nt];
    v += __shfl_xor(v, 16);
    v += __shfl_xor(v, 32);
    if (lane < 16) pS[w*DG + nt*16 + lane] = v;
  }
  __syncthreads();
  if (t < DG)
    hg[g*DG + t] = (pS[t] + pS[DG+t] + pS[2*DG+t] + pS[3*DG+t]) * (1.0f/NPG);
}

// K7: per-graph input projection
__global__ __launch_bounds__(512) void k_proj(const float* __restrict__ hg,
    const float* __restrict__ w_ih, const float* __restrict__ b_ih,
    float* __restrict__ proj) {
  __shared__ __align__(16) float hS[HL];
  int g = blockIdx.x, r = threadIdx.x;
  if (r < HL) hS[r] = hg[g*HL + r];
  __syncthreads();
  const float4* wr = (const float4*)(w_ih + (size_t)r*HL);
  const float4* hv = (const float4*)hS;
  float acc = b_ih[r];
  #pragma unroll
  for (int k4 = 0; k4 < 32; ++k4) {
    float4 w4 = wr[k4]; float4 h4 = hv[k4];
    acc += w4.x*h4.x + w4.y*h4.y + w4.z*h4.z + w4.w*h4.w;
  }
  proj[(size_t)g*G4 + r] = acc;
}

// K8: LSTM v2 — w_hh fp16 CU-RESIDENT in LDS (fp32 streams from L2 were the
// 44 µs bound; allocator refuses 128-float reg arrays — rounds 4/6/9 evidence).
// Layout wL[k4][r] (16 B granules, lane stride 16 B -> 2-way bank alias = free).
// h state packed fp16; products accumulate fp32 via v_dot2_f32_f16.
// Gates/c/activations stay fp32. 64 threads handle hidden PAIRS so the fp16
// h-pack needs no third barrier.
__global__ __launch_bounds__(512) void k_lstm(const float* __restrict__ proj,
    const float* __restrict__ w_hh, const float* __restrict__ b_hh,
    const float* __restrict__ w_fc, const float* __restrict__ b_fc,
    float* __restrict__ out) {
  __shared__ int4 wL[16*512];        // 128 KB: [k4][r] = 8 fp16 of w_hh[r][k4*8..]
  __shared__ float gS[G4];           // 2 KB
  __shared__ __align__(16) int4 hPi[16];  // 128 fp16 packed h state
  int b = blockIdx.x, t = threadIdx.x;
  // stage w_hh fp32 -> fp16 LDS
  for (int i = t; i < 16*512; i += 512) {
    int k4 = i >> 9, r = i & 511;
    const float4* wp = (const float4*)(w_hh + (size_t)r*HL + k4*8);
    float4 w0 = wp[0], w1 = wp[1];
    half2v p0 = {(_Float16)w0.x, (_Float16)w0.y};
    half2v p1 = {(_Float16)w0.z, (_Float16)w0.w};
    half2v p2 = {(_Float16)w1.x, (_Float16)w1.y};
    half2v p3 = {(_Float16)w1.z, (_Float16)w1.w};
    int4 pk;
    pk.x = __builtin_bit_cast(int, p0); pk.y = __builtin_bit_cast(int, p1);
    pk.z = __builtin_bit_cast(int, p2); pk.w = __builtin_bit_cast(int, p3);
    wL[i] = pk;
  }
  if (t < 16) hPi[t] = make_int4(0,0,0,0);
  float bh = b_hh[t];
  float c0 = 0.f, c1 = 0.f;
  __syncthreads();
  for (int l = 0; l < SEQ; ++l) {
    float acc = proj[(size_t)(b+l)*G4 + t] + bh;
    #pragma unroll
    for (int k4 = 0; k4 < 16; ++k4) {
      int4 wv = wL[(k4 << 9) + t];
      int4 hv = hPi[k4];
      acc = h2dot(__builtin_bit_cast(half2v, wv.x), __builtin_bit_cast(half2v, hv.x), acc);
      acc = h2dot(__builtin_bit_cast(half2v, wv.y), __builtin_bit_cast(half2v, hv.y), acc);
      acc = h2dot(__builtin_bit_cast(half2v, wv.z), __builtin_bit_cast(half2v, hv.z), acc);
      acc = h2dot(__builtin_bit_cast(half2v, wv.w), __builtin_bit_cast(half2v, hv.w), acc);
    }
    gS[t] = acc;
    __syncthreads();
    if (t < 64) {
      int j0 = 2*t, j1 = 2*t + 1;
      float i0 = sigmoidf_(gS[j0]),      i1 = sigmoidf_(gS[j1]);
      float f0 = sigmoidf_(gS[HL+j0]),   f1 = sigmoidf_(gS[HL+j1]);
      float g0 = tanhf(gS[2*HL+j0]),     g1 = tanhf(gS[2*HL+j1]);
      float o0 = sigmoidf_(gS[3*HL+j0]), o1 = sigmoidf_(gS[3*HL+j1]);
      c0 = f0*c0 + i0*g0;
      c1 = f1*c1 + i1*g1;
      float h0 = o0 * tanhf(c0);
      float h1 = o1 * tanhf(c1);
      half2v hp = {(_Float16)h0, (_Float16)h1};
      ((int*)hPi)[t] = __builtin_bit_cast(int, hp);
      if (l == SEQ-1) {
        float s = h0*w_fc[j0] + h1*w_fc[j1];
        #pragma unroll
        for (int off = 32; off > 0; off >>= 1) s += __shfl_down(s, off);
        if (t == 0) out[b] = s + b_fc[0];
      }
    }
    __syncthreads();
  }
}

extern "C" void kernel_launch(void* const* d_in, const int* in_sizes, int n_in,
                              void* d_out, int out_size, void* d_ws, size_t ws_size,
                              hipStream_t stream) {
  const float* x     = (const float*)d_in[0];
  const int*   src   = (const int*)d_in[1];
  const int*   dst   = (const int*)d_in[2];
  const float* w_gcn = (const float*)d_in[4];
  const float* b_gcn = (const float*)d_in[5];
  const float* w_ih  = (const float*)d_in[6];
  const float* w_hh  = (const float*)d_in[7];
  const float* b_ih  = (const float*)d_in[8];
  const float* b_hh  = (const float*)d_in[9];
  const float* w_fc  = (const float*)d_in[10];
  const float* b_fc  = (const float*)d_in[11];
  float* out = (float*)d_out;

  char* ws = (char*)d_ws;
  size_t off = 0;
  auto alloc = [&](size_t bytes) -> void* {
    void* p = ws + off; off += (bytes + 255) & ~(size_t)255; return p;
  };
  int* cnt     = (int*)alloc((size_t)NCNT*4);
  int* part    = (int*)alloc((size_t)N_EDGES_*4);
  unsigned short* sorted_all = (unsigned short*)alloc((size_t)N_EDGES_*2);
  float* so_all = (float*)alloc((size_t)N_NODES_*4);
  int* e_end   = (int*)alloc((size_t)N_NODES_*4);
  int* e_deg   = (int*)alloc((size_t)N_NODES_*4);
  ushort4* xsb = (ushort4*)alloc((size_t)N_NODES_*DIN*2);
  unsigned short* hpreb = (unsigned short*)alloc((size_t)N_GRAPHS*NPGP*DIN*2);
  float* hg    = (float*)alloc((size_t)N_GRAPHS*DG*4);
  float* proj  = (float*)alloc((size_t)N_GRAPHS*G4*4);
  (void)ws_size; (void)in_sizes; (void)n_in; (void)out_size;

  k_count<<<NPART, 256, 0, stream>>>(src, cnt);
  k_pscan<<<1, 1024, 0, stream>>>(cnt);
  k_part<<<NPART, 256, 0, stream>>>(src, dst, cnt, part);
  k_sort<<<N_GRAPHS, 512, 0, stream>>>(cnt, part, sorted_all, so_all, e_end, e_deg);
  k_xprep<<<N_GRAPHS, 256, 0, stream>>>(x, so_all, xsb);
  k_agg<<<(N_GRAPHS*NPGP)/4, 256, 0, stream>>>((const int4*)xsb, e_end, e_deg, sorted_all, hpreb);
  k_gcn<<<N_GRAPHS, 256, 0, stream>>>(hpreb, w_gcn, b_gcn, hg);
  k_proj<<<N_GRAPHS, 512, 0, stream>>>(hg, w_ih, b_ih, proj);
  k_lstm<<<BWIN, 512, 0, stream>>>(proj, w_hh, b_hh, w_fc, b_fc, out);
}